// Round 4
// baseline (160.031 us; speedup 1.0000x reference)
//
#include <hip/hip_runtime.h>
#include <stdint.h>

#define N_B 4
#define S_LEN 2048
#define N_H 8
#define E_DIM 512

typedef __attribute__((ext_vector_type(8))) short bf16x8;
typedef __attribute__((ext_vector_type(4))) short bf16x4;
typedef __attribute__((ext_vector_type(4))) float f32x4;
typedef __attribute__((ext_vector_type(4))) unsigned int u32x4;
typedef __attribute__((ext_vector_type(2))) unsigned int u32x2;
typedef __attribute__((ext_vector_type(4))) unsigned short u16x4;
typedef __attribute__((ext_vector_type(8))) unsigned short u16x8;

#define MFMA16(a, b, c) __builtin_amdgcn_mfma_f32_16x16x32_bf16((a), (b), (c), 0, 0, 0)
// K=16 variant: A/B are 4 bf16 (2 VGPRs); A[m=lane&15][k=(lane>>4)*4+j],
// B[k=(lane>>4)*4+j][n=lane&15] == the 16x16 C/D layout -> S^T feeds it directly.
#define MFMA16K16(a, b, c) __builtin_amdgcn_mfma_f32_16x16x16bf16_1k((a), (b), (c), 0, 0, 0)

__device__ __forceinline__ unsigned short f2bf(float f) {
    union { float f; unsigned int u; } v; v.f = f;
    unsigned int r = v.u + 0x7fffu + ((v.u >> 16) & 1u);
    return (unsigned short)(r >> 16);
}

// pack two f32 -> two bf16 (round-half-up) in one u32 via v_perm
__device__ __forceinline__ unsigned int pack2bf(float lo, float hi) {
    union { float f; unsigned int u; } a, b; a.f = lo; b.f = hi;
    return __builtin_amdgcn_perm(b.u + 0x8000u, a.u + 0x8000u, 0x07060302u);
}

// Q pre-scale: 1/sqrt(64) * log2(e)  (fixed-max softmax in exp2 domain;
// |score| <= ~60 so exp2 never overflows/underflows to harmful degree)
#define Q_SCALE 0.18033688f

// ---------------------------------------------------------------------------
// Kernel 1: proj = cos(x+theta); Q,K row-major [BH][S][64] bf16 (Q*Q_SCALE);
//           Vt [BH][64][S] bf16.  grid = 256 chunks x 3 mats = 768 blocks.
// ---------------------------------------------------------------------------
__global__ __launch_bounds__(256) void qkv_kernel(
    const float* __restrict__ x, const float* __restrict__ theta,
    const float* __restrict__ Wq, const float* __restrict__ Wk,
    const float* __restrict__ Wv,
    unsigned short* __restrict__ Q, unsigned short* __restrict__ K,
    unsigned short* __restrict__ Vt)
{
    __shared__ float proj[32][8];
    const int tid = threadIdx.x;
    const int mat = blockIdx.x % 3;
    const int chunk = blockIdx.x / 3;
    const int row0 = chunk * 32;
    const int b = row0 >> 11;
    const int s_in_b = row0 & (S_LEN - 1);

    proj[tid >> 3][tid & 7] = cosf(x[row0 * 8 + tid] + theta[tid & 7]);
    __syncthreads();

    if (mat < 2) {
        const float* W = (mat == 0) ? Wq : Wk;
        const float scale = (mat == 0) ? Q_SCALE : 1.0f;
        unsigned short* outp = (mat == 0) ? Q : K;
        const int eg = (tid & 127) * 4;
        const int sg = (tid >> 7) * 16;
        float w[4][8];
        #pragma unroll
        for (int e = 0; e < 4; ++e)
            #pragma unroll
            for (int n = 0; n < 8; ++n)
                w[e][n] = W[(eg + e) * 8 + n] * scale;
        const int h = eg >> 6, d0 = eg & 63;
        unsigned short* p0 = outp + ((size_t)(b * N_H + h) * S_LEN + s_in_b + sg) * 64 + d0;
        #pragma unroll 4
        for (int s = 0; s < 16; ++s) {
            f32x4 pa = *(const f32x4*)&proj[sg + s][0];
            f32x4 pc = *(const f32x4*)&proj[sg + s][4];
            u16x4 o;
            #pragma unroll
            for (int e = 0; e < 4; ++e) {
                float a = 0.f;
                #pragma unroll
                for (int n = 0; n < 4; ++n)
                    a += pa[n] * w[e][n] + pc[n] * w[e][n + 4];
                o[e] = f2bf(a);
            }
            *(u16x4*)&p0[s * 64] = o;
        }
    } else {
        f32x4 ps[8][2];
        const int sl0 = (tid & 3) * 8;
        #pragma unroll
        for (int k2 = 0; k2 < 8; ++k2) {
            ps[k2][0] = *(const f32x4*)&proj[sl0 + k2][0];
            ps[k2][1] = *(const f32x4*)&proj[sl0 + k2][4];
        }
        const int ecol = tid >> 2;
        for (int pass = 0; pass < 8; ++pass) {
            const int e = pass * 64 + ecol;
            const int h = e >> 6, dd = e & 63;
            float wr[8];
            #pragma unroll
            for (int n = 0; n < 8; ++n) wr[n] = Wv[e * 8 + n];
            u16x8 pk;
            #pragma unroll
            for (int k2 = 0; k2 < 8; ++k2) {
                float acc = 0.f;
                #pragma unroll
                for (int n = 0; n < 4; ++n)
                    acc += ps[k2][0][n] * wr[n] + ps[k2][1][n] * wr[n + 4];
                pk[k2] = f2bf(acc);
            }
            *(u16x8*)&Vt[((size_t)(b * N_H + h) * 64 + dd) * S_LEN + s_in_b + sl0] = pk;
        }
    }
}

// ---------------------------------------------------------------------------
// Kernel 2: flash attention, fixed-max softmax, P kept IN REGISTERS:
// S^T = K.Q^T via 16x16x32 (C-layout k=quad*4+r, q=lq), P = exp2(S^T) packed
// to bf16 in-register = B-operand of 16x16x16 MFMA; O^T = Vt . P^T.
// LDS: kt + vt tiles only (stride 66 to spread banks). grid 512 x 256 thr.
// ---------------------------------------------------------------------------
__global__ __launch_bounds__(256, 2) void flash_kernel(
    const unsigned short* __restrict__ Q, const unsigned short* __restrict__ K,
    const unsigned short* __restrict__ Vt, unsigned short* __restrict__ O)
{
    __shared__ short kt[64 * 66];     // K-tile [k][d], stride 66 (1 word mod 32)
    __shared__ short vt[64 * 66];     // V-tile [d][s], stride 66

    const int tid = threadIdx.x;
    const int lane = tid & 63, w = tid >> 6;
    const int quad = lane >> 4, lq = lane & 15;
    const int qt = blockIdx.x & 15, bh = blockIdx.x >> 4;
    const int b = bh >> 3, h = bh & 7;

    const unsigned short* Qb = Q + (size_t)bh * S_LEN * 64;
    const unsigned short* Kb = K + (size_t)bh * S_LEN * 64;
    const unsigned short* Vb = Vt + (size_t)bh * 64 * S_LEN;

    // Q fragments (B-operand of 16x16x32): lane holds Q[q=lq][d=quad*8+j]
    bf16x8 qf[2][2];
    #pragma unroll
    for (int mt = 0; mt < 2; ++mt)
        #pragma unroll
        for (int ks = 0; ks < 2; ++ks)
            qf[mt][ks] = *(const bf16x8*)&Qb[(size_t)(qt * 128 + w * 32 + mt * 16 + lq) * 64 + ks * 32 + quad * 8];

    // O^T accumulators: C-layout col=q=lq, row=d=dblk*16+quad*4+r
    f32x4 oT[2][4];
    #pragma unroll
    for (int mt = 0; mt < 2; ++mt)
        #pragma unroll
        for (int dblk = 0; dblk < 4; ++dblk) oT[mt][dblk] = 0.f;
    float lsum[2] = {0.f, 0.f};

    // preload tile 0
    u32x4 pkr[2], pvr[2];
    #pragma unroll
    for (int i = 0; i < 2; ++i) {
        const int u = tid + (i << 8);
        pkr[i] = *(const u32x4*)&Kb[(size_t)(u >> 3) * 64 + (u & 7) * 8];
        pvr[i] = *(const u32x4*)&Vb[(size_t)(u >> 3) * S_LEN + (u & 7) * 8];
    }

    for (int kti = 0; kti < 32; ++kti) {
        __syncthreads();
        #pragma unroll
        for (int i = 0; i < 2; ++i) {
            const int u = tid + (i << 8);
            *(u32x4*)&kt[(u >> 3) * 66 + (u & 7) * 8] = pkr[i];
            *(u32x4*)&vt[(u >> 3) * 66 + (u & 7) * 8] = pvr[i];
        }
        __syncthreads();

        const int kb2 = (kti < 31) ? (kti + 1) * 64 : 0;
        #pragma unroll
        for (int i = 0; i < 2; ++i) {
            const int u = tid + (i << 8);
            pkr[i] = *(const u32x4*)&Kb[(size_t)(kb2 + (u >> 3)) * 64 + (u & 7) * 8];
            pvr[i] = *(const u32x4*)&Vb[(size_t)(u >> 3) * S_LEN + kb2 + (u & 7) * 8];
        }

        // S^T = K . Q^T
        f32x4 sacc[2][4];
        #pragma unroll
        for (int mt = 0; mt < 2; ++mt)
            #pragma unroll
            for (int mts = 0; mts < 4; ++mts) sacc[mt][mts] = 0.f;
        #pragma unroll
        for (int mts = 0; mts < 4; ++mts) {
            #pragma unroll
            for (int ks = 0; ks < 2; ++ks) {
                bf16x8 af = *(const bf16x8*)&kt[(mts * 16 + lq) * 66 + ks * 32 + quad * 8];
                sacc[0][mts] = MFMA16(af, qf[0][ks], sacc[0][mts]);
                sacc[1][mts] = MFMA16(af, qf[1][ks], sacc[1][mts]);
            }
        }

        // P = exp2(S^T) packed to bf16 in-register (B-operand of 16x16x16)
        bf16x4 pfrag[2][4];
        #pragma unroll
        for (int mt = 0; mt < 2; ++mt) {
            #pragma unroll
            for (int mts = 0; mts < 4; ++mts) {
                f32x4 p;
                #pragma unroll
                for (int e = 0; e < 4; ++e) p[e] = exp2f(sacc[mt][mts][e]);
                lsum[mt] += (p[0] + p[1]) + (p[2] + p[3]);
                union { u32x2 u; bf16x4 s; } cv;
                cv.u[0] = pack2bf(p[0], p[1]);
                cv.u[1] = pack2bf(p[2], p[3]);
                pfrag[mt][mts] = cv.s;
            }
        }

        // O^T += Vt . P^T   (A-frag: Vt[d=dblk*16+lq][k=mts*16+quad*4..+3])
        #pragma unroll
        for (int dblk = 0; dblk < 4; ++dblk) {
            #pragma unroll
            for (int mts = 0; mts < 4; ++mts) {
                bf16x4 vf = *(const bf16x4*)&vt[(dblk * 16 + lq) * 66 + mts * 16 + quad * 4];
                oT[0][dblk] = MFMA16K16(vf, pfrag[0][mts], oT[0][dblk]);
                oT[1][dblk] = MFMA16K16(vf, pfrag[1][mts], oT[1][dblk]);
            }
        }
    }

    // epilogue: lsum per lane covers k=quad*4+r blocks -> reduce across quads.
    // O^T C-layout: col=q=lq (normalizer is per-lane!), row=d=dblk*16+quad*4+r.
    #pragma unroll
    for (int mt = 0; mt < 2; ++mt) {
        float rs = lsum[mt];
        rs += __shfl_xor(rs, 16);
        rs += __shfl_xor(rs, 32);
        const float inv = 1.0f / rs;
        const int q = qt * 128 + w * 32 + mt * 16 + lq;
        unsigned short* dst = &O[((size_t)b * S_LEN + q) * E_DIM + h * 64];
        #pragma unroll
        for (int dblk = 0; dblk < 4; ++dblk) {
            u16x4 o;
            #pragma unroll
            for (int r = 0; r < 4; ++r) o[r] = f2bf(oT[mt][dblk][r] * inv);
            *(u16x4*)&dst[dblk * 16 + quad * 4] = o;
        }
    }
}

// ---------------------------------------------------------------------------
// Kernel 3: Y[m][f] = sum_e O[m][e]*Wc[f][e]. Wc f-slice (64x512) staged to
// LDS ONCE as bf16; O A-frags streamed from global (16B contiguous). No
// per-iter barriers. grid = 32 m-tiles(256 rows) x 8 f-tiles = 256 blocks.
// ---------------------------------------------------------------------------
__global__ __launch_bounds__(256) void outproj_kernel(
    const unsigned short* __restrict__ O, const float* __restrict__ Wc,
    float* __restrict__ Y)
{
    __shared__ short wl[64 * 514];   // 64 f-rows x 512 e, stride 514 (~66KB)
    const int tid = threadIdx.x;
    const int lane = tid & 63, w = tid >> 6;
    const int quad = lane >> 4, lq = lane & 15;
    const int f0 = (blockIdx.x & 7) * 64;
    const int m0 = (blockIdx.x >> 3) * 256;

    // stage Wc[f0:f0+64][0:512] -> bf16 LDS
    #pragma unroll
    for (int i = 0; i < 32; ++i) {
        const int u = tid + (i << 8);
        const int r = u >> 7, c4 = (u & 127) * 4;
        f32x4 fv = *(const f32x4*)&Wc[(size_t)(f0 + r) * E_DIM + c4];
        u16x4 pk = { f2bf(fv[0]), f2bf(fv[1]), f2bf(fv[2]), f2bf(fv[3]) };
        *(u16x4*)&wl[r * 514 + c4] = pk;
    }
    __syncthreads();

    // wave w: rows m0 + w*64 .. +63, two chunks of 32
    #pragma unroll
    for (int mo = 0; mo < 2; ++mo) {
        const int mbase = m0 + w * 64 + mo * 32;
        f32x4 acc[2][4];
        #pragma unroll
        for (int mt = 0; mt < 2; ++mt)
            #pragma unroll
            for (int nt = 0; nt < 4; ++nt) acc[mt][nt] = 0.f;

        #pragma unroll 4
        for (int ks = 0; ks < 16; ++ks) {
            bf16x8 af[2];
            #pragma unroll
            for (int mt = 0; mt < 2; ++mt)
                af[mt] = *(const bf16x8*)&O[(size_t)(mbase + mt * 16 + lq) * E_DIM + ks * 32 + quad * 8];
            #pragma unroll
            for (int nt = 0; nt < 4; ++nt) {
                bf16x8 bf = *(const bf16x8*)&wl[(nt * 16 + lq) * 514 + ks * 32 + quad * 8];
                acc[0][nt] = MFMA16(af[0], bf, acc[0][nt]);
                acc[1][nt] = MFMA16(af[1], bf, acc[1][nt]);
            }
        }

        #pragma unroll
        for (int mt = 0; mt < 2; ++mt)
            #pragma unroll
            for (int nt = 0; nt < 4; ++nt)
                #pragma unroll
                for (int r = 0; r < 4; ++r)
                    Y[(size_t)(mbase + mt * 16 + quad * 4 + r) * E_DIM + f0 + nt * 16 + lq] = acc[mt][nt][r];
    }
}

// ---------------------------------------------------------------------------
extern "C" void kernel_launch(void* const* d_in, const int* in_sizes, int n_in,
                              void* d_out, int out_size, void* d_ws, size_t ws_size,
                              hipStream_t stream) {
    const float* x     = (const float*)d_in[0];
    const float* theta = (const float*)d_in[1];
    const float* Wq    = (const float*)d_in[2];
    const float* Wk    = (const float*)d_in[3];
    const float* Wv    = (const float*)d_in[4];
    const float* Wc    = (const float*)d_in[5];
    float* Y = (float*)d_out;

    char* ws = (char*)d_ws;
    unsigned short* Q  = (unsigned short*)(ws);                      // 8 MB
    unsigned short* K  = (unsigned short*)(ws + ((size_t)8 << 20));  // 8 MB
    unsigned short* Vt = (unsigned short*)(ws + ((size_t)16 << 20)); // 8 MB
    unsigned short* O  = (unsigned short*)(ws + ((size_t)24 << 20)); // 8 MB

    qkv_kernel<<<(N_B * S_LEN / 32) * 3, 256, 0, stream>>>(x, theta, Wq, Wk, Wv, Q, K, Vt);
    flash_kernel<<<N_B * N_H * (S_LEN / 128), 256, 0, stream>>>(Q, K, Vt, O);
    outproj_kernel<<<(N_B * S_LEN / 256) * (E_DIM / 64), 256, 0, stream>>>(O, Wc, Y);
}